// Round 5
// baseline (549.501 us; speedup 1.0000x reference)
//
#include <hip/hip_runtime.h>

#define N_NODES 100000
#define E_EDGES 1600000
#define F_DIM 128
#define ALPHA 0.2f

#define BSHIFT 7
#define N_BUCKETS ((N_NODES + 127) >> 7)      // 782
#define SCORE_BLOCKS (N_NODES / 4)            // 25000 (4 nodes per 256-thr block)
#define HISTA_BLOCKS 256                      // grid-stride bucket-histogram blocks

// ---------------------------------------------------------------------------
// K1: fused per-node score (blocks [0, SCORE_BLOCKS)) + coarse bucket
// histogram of src>>7 (remaining blocks, LDS-aggregated).
// ---------------------------------------------------------------------------
__global__ void fused_score_hist_kernel(const float* __restrict__ h,
                                        const float* __restrict__ a,
                                        float* __restrict__ s_left,
                                        float* __restrict__ s_right,
                                        const int* __restrict__ src,
                                        int* __restrict__ bcnt) {
    __shared__ int lh[N_BUCKETS];
    const int b = blockIdx.x;
    if (b < SCORE_BLOCKS) {
        const int node = b * 4 + (threadIdx.x >> 6);
        const int lane = threadIdx.x & 63;

        const float2 hv = reinterpret_cast<const float2*>(h + (size_t)node * F_DIM)[lane];
        const float2 al = reinterpret_cast<const float2*>(a)[lane];
        const float2 ar = reinterpret_cast<const float2*>(a + F_DIM)[lane];

        float pl = hv.x * al.x + hv.y * al.y;
        float pr = hv.x * ar.x + hv.y * ar.y;

        #pragma unroll
        for (int off = 32; off > 0; off >>= 1) {
            pl += __shfl_down(pl, off);
            pr += __shfl_down(pr, off);
        }
        if (lane == 0) {
            s_left[node]  = pl;
            s_right[node] = pr;
        }
    } else {
        const int hb = b - SCORE_BLOCKS;
        for (int i = threadIdx.x; i < N_BUCKETS; i += 256) lh[i] = 0;
        __syncthreads();
        for (int i = hb * 256 + threadIdx.x; i < E_EDGES; i += HISTA_BLOCKS * 256)
            atomicAdd(&lh[src[i] >> BSHIFT], 1);
        __syncthreads();
        for (int i = threadIdx.x; i < N_BUCKETS; i += 256)
            if (lh[i]) atomicAdd(&bcnt[i], lh[i]);
    }
}

// ---------------------------------------------------------------------------
// K2: exclusive scan of the 782 bucket counts (one 1024-thread block).
// Writes bbase[0..NB] (with total at NB), bcur = bbase, and the row_start
// sentinel.
// ---------------------------------------------------------------------------
__global__ void bucket_scan_kernel(const int* __restrict__ bcnt,
                                   int* __restrict__ bbase,
                                   int* __restrict__ bcur,
                                   int* __restrict__ row_start) {
    __shared__ int s[1024];
    const int tid = threadIdx.x;
    const int v = (tid < N_BUCKETS) ? bcnt[tid] : 0;
    s[tid] = v;
    __syncthreads();
    #pragma unroll
    for (int off = 1; off < 1024; off <<= 1) {
        int t = (tid >= off) ? s[tid - off] : 0;
        __syncthreads();
        s[tid] += t;
        __syncthreads();
    }
    if (tid < N_BUCKETS) {
        const int e = s[tid] - v;   // exclusive
        bbase[tid] = e;
        bcur[tid]  = e;
    }
    if (tid == 0) {
        bbase[N_BUCKETS] = s[1023];         // == E_EDGES
        row_start[N_NODES] = E_EDGES;       // sentinel
    }
}

// ---------------------------------------------------------------------------
// K3: scatter each edge into its coarse bucket as a packed 4B record
// (src&127)<<17 | dst  (dst < 2^17). Bucket frontier lines fill fast ->
// near-perfect L2 write combining (vs. per-src scatter's line thrash).
// ---------------------------------------------------------------------------
__global__ void bucket_scatter_kernel(const int* __restrict__ src,
                                      const int* __restrict__ dst,
                                      int* __restrict__ bcur,
                                      unsigned int* __restrict__ bucket_arr) {
    const int e = blockIdx.x * blockDim.x + threadIdx.x;
    if (e >= E_EDGES) return;
    const int s = src[e];
    const int d = dst[e];
    const unsigned int rec = ((unsigned int)(s & 127) << 17) | (unsigned int)d;
    const int pos = atomicAdd(&bcur[s >> BSHIFT], 1);
    bucket_arr[pos] = rec;
}

// ---------------------------------------------------------------------------
// K4: per-bucket counting sort (128 bins in LDS) + edge-weight compute +
// coalesced pairs/row_start emission. One 256-thread block per bucket.
// ---------------------------------------------------------------------------
__global__ void bucket_sort_kernel(const unsigned int* __restrict__ bucket_arr,
                                   const int* __restrict__ bbase,
                                   const float* __restrict__ s_left,
                                   const float* __restrict__ s_right,
                                   int* __restrict__ row_start,
                                   int2* __restrict__ pairs) {
    __shared__ int cnt[128];
    __shared__ int start[128];
    __shared__ int cur[128];
    __shared__ float sl[128];

    const int b = blockIdx.x;
    const int tid = threadIdx.x;
    const int base = bbase[b];
    const int endb = bbase[b + 1];
    const int srcbase = b << BSHIFT;
    const int nsrc = min(128, N_NODES - srcbase);

    if (tid < 128) {
        cnt[tid] = 0;
        if (tid < nsrc) sl[tid] = s_left[srcbase + tid];
    }
    __syncthreads();

    for (int i = base + tid; i < endb; i += 256)
        atomicAdd(&cnt[bucket_arr[i] >> 17], 1);
    __syncthreads();

    if (tid < 64) {   // full wave 0: scan 128 bins
        const int lane = tid;
        const int c0 = cnt[lane], c1 = cnt[64 + lane];
        int v0 = c0, v1 = c1;
        #pragma unroll
        for (int off = 1; off < 64; off <<= 1) {
            int t0 = __shfl_up(v0, off);
            int t1 = __shfl_up(v1, off);
            if (lane >= off) { v0 += t0; v1 += t1; }
        }
        const int tot0 = __shfl(v0, 63);
        v1 += tot0;
        const int e0 = v0 - c0, e1 = v1 - c1;   // exclusive
        start[lane] = e0;  start[64 + lane] = e1;
        cur[lane]   = e0;  cur[64 + lane]   = e1;
        if (lane < nsrc)      row_start[srcbase + lane]      = base + e0;
        if (64 + lane < nsrc) row_start[srcbase + 64 + lane] = base + e1;
    }
    __syncthreads();

    for (int i = base + tid; i < endb; i += 256) {
        const unsigned int rec = bucket_arr[i];
        const int ls = rec >> 17;
        const int d  = rec & 0x1FFFF;
        const float score = sl[ls] + s_right[d];
        const float lr = score > 0.0f ? score : ALPHA * score;
        const float ee = __expf(-lr);
        const int pos = base + atomicAdd(&cur[ls], 1);
        pairs[pos] = make_int2(d, __float_as_int(ee));
    }
}

// ---------------------------------------------------------------------------
// K5: gather. One wave per node; two 32-lane halves each cover the 128-f row
// as float4. All loop bounds wave-uniform; only shfl SOURCE index differs per
// lane. Unrolled to 8 edges per half (16 h-lines in flight per wave).
// ---------------------------------------------------------------------------
__global__ void gather_kernel(const float* __restrict__ h,
                              const int* __restrict__ row_start,
                              const int2* __restrict__ pairs,
                              float* __restrict__ out) {
    const int gtid = blockIdx.x * blockDim.x + threadIdx.x;
    const int node = gtid >> 6;
    const int lane = threadIdx.x & 63;
    if (node >= N_NODES) return;

    const int beg = row_start[node];
    const int end = row_start[node + 1];

    const int half = lane >> 5;
    const int hl   = lane & 31;
    const float4* __restrict__ h4 = reinterpret_cast<const float4*>(h);

    float4 acc = make_float4(0.0f, 0.0f, 0.0f, 0.0f);
    float rs = 0.0f;

    for (int base = beg; base < end; base += 64) {
        const int m = min(64, end - base);   // wave-uniform
        int pd = 0; float pe = 0.0f;
        if (lane < m) {
            const int2 pr = pairs[base + lane];
            pd = pr.x;
            pe = __int_as_float(pr.y);
        }

        int j = 0;  // uniform in all lanes from here
        for (; j + 16 <= m; j += 16) {
            const int jj = j + half;
            int   d[8]; float e[8];
            #pragma unroll
            for (int k = 0; k < 8; ++k) {
                d[k] = __shfl(pd, jj + 2 * k);
                e[k] = __shfl(pe, jj + 2 * k);
            }
            float4 v[8];
            #pragma unroll
            for (int k = 0; k < 8; ++k) v[k] = h4[(size_t)d[k] * 32 + hl];
            #pragma unroll
            for (int k = 0; k < 8; ++k) {
                rs    += e[k];
                acc.x += e[k] * v[k].x;
                acc.y += e[k] * v[k].y;
                acc.z += e[k] * v[k].z;
                acc.w += e[k] * v[k].w;
            }
        }
        for (; j + 8 <= m; j += 8) {
            const int jj = j + half;
            int   d[4]; float e[4];
            #pragma unroll
            for (int k = 0; k < 4; ++k) {
                d[k] = __shfl(pd, jj + 2 * k);
                e[k] = __shfl(pe, jj + 2 * k);
            }
            float4 v[4];
            #pragma unroll
            for (int k = 0; k < 4; ++k) v[k] = h4[(size_t)d[k] * 32 + hl];
            #pragma unroll
            for (int k = 0; k < 4; ++k) {
                rs    += e[k];
                acc.x += e[k] * v[k].x;
                acc.y += e[k] * v[k].y;
                acc.z += e[k] * v[k].z;
                acc.w += e[k] * v[k].w;
            }
        }
        for (; j + 2 <= m; j += 2) {
            const int jj = j + half;
            const int   dd = __shfl(pd, jj);
            const float ee = __shfl(pe, jj);
            const float4 v = h4[(size_t)dd * 32 + hl];
            rs += ee;
            acc.x += ee * v.x;
            acc.y += ee * v.y;
            acc.z += ee * v.z;
            acc.w += ee * v.w;
        }
        if (j < m) {                          // single leftover edge
            const int   dd = __shfl(pd, j);   // uniform source
            float       ee = __shfl(pe, j);
            if (half == 1) ee = 0.0f;
            const float4 v = h4[(size_t)dd * 32 + hl];
            rs += ee;
            acc.x += ee * v.x;
            acc.y += ee * v.y;
            acc.z += ee * v.z;
            acc.w += ee * v.w;
        }
    }

    acc.x += __shfl_xor(acc.x, 32);
    acc.y += __shfl_xor(acc.y, 32);
    acc.z += __shfl_xor(acc.z, 32);
    acc.w += __shfl_xor(acc.w, 32);
    rs    += __shfl_xor(rs, 32);

    if (half == 0) {
        const float inv = 1.0f / rs;
        float4 o;
        o.x = fmaxf(acc.x * inv, 0.0f);
        o.y = fmaxf(acc.y * inv, 0.0f);
        o.z = fmaxf(acc.z * inv, 0.0f);
        o.w = fmaxf(acc.w * inv, 0.0f);
        reinterpret_cast<float4*>(out)[(size_t)node * 32 + hl] = o;
    }
}

// ---------------------------------------------------------------------------
// Fallback (atomic path) if ws_size is too small.
// ---------------------------------------------------------------------------
__global__ void score_kernel(const float* __restrict__ h,
                             const float* __restrict__ a,
                             float* __restrict__ s_left,
                             float* __restrict__ s_right) {
    const int gtid = blockIdx.x * blockDim.x + threadIdx.x;
    const int node = gtid >> 6;
    const int lane = threadIdx.x & 63;
    if (node >= N_NODES) return;
    const float2 hv = reinterpret_cast<const float2*>(h + (size_t)node * F_DIM)[lane];
    const float2 al = reinterpret_cast<const float2*>(a)[lane];
    const float2 ar = reinterpret_cast<const float2*>(a + F_DIM)[lane];
    float pl = hv.x * al.x + hv.y * al.y;
    float pr = hv.x * ar.x + hv.y * ar.y;
    #pragma unroll
    for (int off = 32; off > 0; off >>= 1) {
        pl += __shfl_down(pl, off);
        pr += __shfl_down(pr, off);
    }
    if (lane == 0) { s_left[node] = pl; s_right[node] = pr; }
}

__global__ void edge_atomic_kernel(const float* __restrict__ h,
                                   const int* __restrict__ src,
                                   const int* __restrict__ dst,
                                   const float* __restrict__ s_left,
                                   const float* __restrict__ s_right,
                                   float* __restrict__ out,
                                   float* __restrict__ rowsum) {
    const int gtid = blockIdx.x * blockDim.x + threadIdx.x;
    const int e = gtid >> 6;
    const int lane = threadIdx.x & 63;
    if (e >= E_EDGES) return;
    const int s = src[e];
    const int d = dst[e];
    const float score = s_left[s] + s_right[d];
    const float lr = score > 0.0f ? score : ALPHA * score;
    const float ee = __expf(-lr);
    if (lane == 0) atomicAdd(&rowsum[s], ee);
    const float2 hv = reinterpret_cast<const float2*>(h + (size_t)d * F_DIM)[lane];
    float* o = out + (size_t)s * F_DIM + (size_t)lane * 2;
    atomicAdd(o,     ee * hv.x);
    atomicAdd(o + 1, ee * hv.y);
}

__global__ void finalize_kernel(float* __restrict__ out,
                                const float* __restrict__ rowsum) {
    const int i = blockIdx.x * blockDim.x + threadIdx.x;
    const int total = N_NODES * (F_DIM / 4);
    if (i >= total) return;
    const int n = i / (F_DIM / 4);
    const float inv = 1.0f / rowsum[n];
    float4 v = reinterpret_cast<float4*>(out)[i];
    v.x = fmaxf(v.x * inv, 0.0f);
    v.y = fmaxf(v.y * inv, 0.0f);
    v.z = fmaxf(v.z * inv, 0.0f);
    v.w = fmaxf(v.w * inv, 0.0f);
    reinterpret_cast<float4*>(out)[i] = v;
}

extern "C" void kernel_launch(void* const* d_in, const int* in_sizes, int n_in,
                              void* d_out, int out_size, void* d_ws, size_t ws_size,
                              hipStream_t stream) {
    const float* h    = (const float*)d_in[0];   // [N, F]
    const float* a    = (const float*)d_in[1];   // [1, 2F]
    const int*   edge = (const int*)d_in[2];     // [2, E]
    const int*   src  = edge;
    const int*   dst  = edge + E_EDGES;
    float* out = (float*)d_out;

    // bucket_arr scratch lives in d_out's first 6.4 MB: fully consumed by
    // bucket_sort before gather rewrites every element of out.
    unsigned int* bucket_arr = (unsigned int*)d_out;

    // --- workspace layout (~14.0 MB) ---
    char* wp = (char*)d_ws;
    int2*  pairs    = (int2*)wp;      wp += (size_t)E_EDGES * sizeof(int2);
    float* s_left   = (float*)wp;     wp += (size_t)N_NODES * sizeof(float);
    float* s_right  = (float*)wp;     wp += (size_t)N_NODES * sizeof(float);
    int*   row_start= (int*)wp;       wp += (size_t)(N_NODES + 1) * sizeof(int);
    int*   bcnt     = (int*)wp;       wp += N_BUCKETS * sizeof(int);
    int*   bbase    = (int*)wp;       wp += (N_BUCKETS + 1) * sizeof(int);
    int*   bcur     = (int*)wp;       wp += N_BUCKETS * sizeof(int);
    const size_t needed = (size_t)(wp - (char*)d_ws);

    const int wpb = 256 / 64;

    if (ws_size < needed) {
        // -------- fallback: atomic path (needs only 1.2 MB) --------
        float* fsl = (float*)d_ws;
        float* fsr = fsl + N_NODES;
        float* frs = fsr + N_NODES;
        hipMemsetAsync(d_out, 0, (size_t)N_NODES * F_DIM * sizeof(float), stream);
        hipMemsetAsync(frs, 0, (size_t)N_NODES * sizeof(float), stream);
        score_kernel<<<(N_NODES + wpb - 1) / wpb, 256, 0, stream>>>(h, a, fsl, fsr);
        edge_atomic_kernel<<<(E_EDGES + wpb - 1) / wpb, 256, 0, stream>>>(
            h, src, dst, fsl, fsr, out, frs);
        const int total = N_NODES * (F_DIM / 4);
        finalize_kernel<<<(total + 255) / 256, 256, 0, stream>>>(out, frs);
        return;
    }

    hipMemsetAsync(bcnt, 0, N_BUCKETS * sizeof(int), stream);

    fused_score_hist_kernel<<<SCORE_BLOCKS + HISTA_BLOCKS, 256, 0, stream>>>(
        h, a, s_left, s_right, src, bcnt);

    bucket_scan_kernel<<<1, 1024, 0, stream>>>(bcnt, bbase, bcur, row_start);

    bucket_scatter_kernel<<<(E_EDGES + 255) / 256, 256, 0, stream>>>(
        src, dst, bcur, bucket_arr);

    bucket_sort_kernel<<<N_BUCKETS, 256, 0, stream>>>(
        bucket_arr, bbase, s_left, s_right, row_start, pairs);

    gather_kernel<<<(N_NODES + wpb - 1) / wpb, 256, 0, stream>>>(
        h, row_start, pairs, out);
}

// Round 6
// 247.385 us; speedup vs baseline: 2.2212x; 2.2212x over previous
//
#include <hip/hip_runtime.h>

#define N_NODES 100000
#define E_EDGES 1600000
#define F_DIM 128
#define ALPHA 0.2f

#define SCAN_BLOCK 1024
#define NUM_SCAN_BLOCKS ((N_NODES + SCAN_BLOCK - 1) / SCAN_BLOCK)  // 98

#define SCORE_BLOCKS (N_NODES / 4)            // 25000 (4 nodes per 256-thr block)
#define HIST_BLOCKS  (E_EDGES / 256)          // 6250

__device__ __forceinline__ float bf2f(unsigned short s) {
    return __uint_as_float((unsigned)s << 16);
}
__device__ __forceinline__ unsigned short f2bf(float f) {
    unsigned u = __float_as_uint(f);
    return (unsigned short)((u + 0x7FFFu + ((u >> 16) & 1u)) >> 16);  // RNE
}

// ---------------------------------------------------------------------------
// K1: fused per-node score + h->bf16 copy (blocks [0, SCORE_BLOCKS)) and
// per-src histogram (remaining blocks; 1.6M int atomics on 100K addrs = ~16
// per address -> contention-free; r5 showed 782 addrs is catastrophic).
// ---------------------------------------------------------------------------
__global__ void fused_score_hist_kernel(const float* __restrict__ h,
                                        const float* __restrict__ a,
                                        float* __restrict__ s_left,
                                        float* __restrict__ s_right,
                                        unsigned short* __restrict__ h_bf16,
                                        const int* __restrict__ src,
                                        int* __restrict__ counts) {
    const int b = blockIdx.x;
    if (b < SCORE_BLOCKS) {
        const int node = b * 4 + (threadIdx.x >> 6);
        const int lane = threadIdx.x & 63;

        const float2 hv = reinterpret_cast<const float2*>(h + (size_t)node * F_DIM)[lane];
        const float2 al = reinterpret_cast<const float2*>(a)[lane];
        const float2 ar = reinterpret_cast<const float2*>(a + F_DIM)[lane];

        // bf16 copy of the row (coalesced 4B/lane)
        ushort2 hb;
        hb.x = f2bf(hv.x);
        hb.y = f2bf(hv.y);
        reinterpret_cast<ushort2*>(h_bf16 + (size_t)node * F_DIM)[lane] = hb;

        float pl = hv.x * al.x + hv.y * al.y;
        float pr = hv.x * ar.x + hv.y * ar.y;

        #pragma unroll
        for (int off = 32; off > 0; off >>= 1) {
            pl += __shfl_down(pl, off);
            pr += __shfl_down(pr, off);
        }
        if (lane == 0) {
            s_left[node]  = pl;
            s_right[node] = pr;
        }
    } else {
        const int e = (b - SCORE_BLOCKS) * 256 + threadIdx.x;
        if (e < E_EDGES) atomicAdd(&counts[src[e]], 1);
    }
}

// ---------------------------------------------------------------------------
// K2a: per-block exclusive scan (1024/block) + block totals.
// ---------------------------------------------------------------------------
__global__ void scan_block_kernel(const int* __restrict__ counts,
                                  int* __restrict__ row_start,
                                  int* __restrict__ partials) {
    __shared__ int s[SCAN_BLOCK];
    const int tid = threadIdx.x;
    const int i = blockIdx.x * SCAN_BLOCK + tid;
    const int v = (i < N_NODES) ? counts[i] : 0;
    s[tid] = v;
    __syncthreads();
    #pragma unroll
    for (int off = 1; off < SCAN_BLOCK; off <<= 1) {
        int t = (tid >= off) ? s[tid - off] : 0;
        __syncthreads();
        s[tid] += t;
        __syncthreads();
    }
    if (i < N_NODES) row_start[i] = s[tid] - v;                // block-local exclusive
    if (tid == SCAN_BLOCK - 1) partials[blockIdx.x] = s[tid];  // block total
}

// ---------------------------------------------------------------------------
// K2b: exclusive scan of block partials (98 <= 128), one block.
// ---------------------------------------------------------------------------
__global__ void scan_partials_kernel(int* __restrict__ partials) {
    __shared__ int s[128];
    const int tid = threadIdx.x;
    const int v = (tid < NUM_SCAN_BLOCKS) ? partials[tid] : 0;
    s[tid] = v;
    __syncthreads();
    #pragma unroll
    for (int off = 1; off < 128; off <<= 1) {
        int t = (tid >= off) ? s[tid - off] : 0;
        __syncthreads();
        s[tid] += t;
        __syncthreads();
    }
    if (tid < NUM_SCAN_BLOCKS) partials[tid] = s[tid] - v;  // exclusive
}

// ---------------------------------------------------------------------------
// K2c: make row_start absolute, init cursor, write sentinel.
// (Cheap 100K-thread pass; saves 2 random gathers/edge in scatter and
// 2 gathers/node in gather vs. the on-the-fly variant.)
// ---------------------------------------------------------------------------
__global__ void add_offsets_kernel(int* __restrict__ row_start,
                                   const int* __restrict__ partials,
                                   int* __restrict__ cursor) {
    const int i = blockIdx.x * blockDim.x + threadIdx.x;
    if (i < N_NODES) {
        const int v = row_start[i] + partials[i >> 10];
        row_start[i] = v;
        cursor[i] = v;
    }
    if (i == 0) row_start[N_NODES] = E_EDGES;
}

// ---------------------------------------------------------------------------
// K3: scatter edges into CSR slots as packed {dst, bitcast(ee)}.
// 100K cursor addresses -> ~16 atomics/address, contention-free.
// ---------------------------------------------------------------------------
__global__ void scatter_kernel(const int* __restrict__ src,
                               const int* __restrict__ dst,
                               const float* __restrict__ s_left,
                               const float* __restrict__ s_right,
                               int* __restrict__ cursor,
                               int2* __restrict__ pairs) {
    const int e = blockIdx.x * blockDim.x + threadIdx.x;
    if (e >= E_EDGES) return;
    const int s = src[e];
    const int d = dst[e];
    const float score = s_left[s] + s_right[d];
    const float lr = score > 0.0f ? score : ALPHA * score;
    const float ee = __expf(-lr);
    const int pos = atomicAdd(&cursor[s], 1);
    pairs[pos] = make_int2(d, __float_as_int(ee));
}

// ---------------------------------------------------------------------------
// K4 (bf16): gather from the bf16 copy of h (256B/row -> half the fabric
// traffic of f32). One wave per node; two 32-lane halves; all loop bounds
// wave-uniform (r3 lesson); unroll 8 edges per half.
// ---------------------------------------------------------------------------
__global__ void gather_bf16_kernel(const unsigned short* __restrict__ h_bf16,
                                   const int* __restrict__ row_start,
                                   const int2* __restrict__ pairs,
                                   float* __restrict__ out) {
    const int gtid = blockIdx.x * blockDim.x + threadIdx.x;
    const int node = gtid >> 6;
    const int lane = threadIdx.x & 63;
    if (node >= N_NODES) return;

    const int beg = row_start[node];
    const int end = row_start[node + 1];

    const int half = lane >> 5;
    const int hl   = lane & 31;
    const ushort4* __restrict__ hb4 = reinterpret_cast<const ushort4*>(h_bf16);

    float4 acc = make_float4(0.0f, 0.0f, 0.0f, 0.0f);
    float rs = 0.0f;

    for (int base = beg; base < end; base += 64) {
        const int m = min(64, end - base);   // wave-uniform
        int pd = 0; float pe = 0.0f;
        if (lane < m) {
            const int2 pr = pairs[base + lane];
            pd = pr.x;
            pe = __int_as_float(pr.y);
        }

        int j = 0;  // uniform across all lanes from here
        for (; j + 16 <= m; j += 16) {
            const int jj = j + half;
            int   d[8]; float e[8];
            #pragma unroll
            for (int k = 0; k < 8; ++k) {
                d[k] = __shfl(pd, jj + 2 * k);
                e[k] = __shfl(pe, jj + 2 * k);
            }
            ushort4 u[8];
            #pragma unroll
            for (int k = 0; k < 8; ++k) u[k] = hb4[(size_t)d[k] * 32 + hl];
            #pragma unroll
            for (int k = 0; k < 8; ++k) {
                rs    += e[k];
                acc.x += e[k] * bf2f(u[k].x);
                acc.y += e[k] * bf2f(u[k].y);
                acc.z += e[k] * bf2f(u[k].z);
                acc.w += e[k] * bf2f(u[k].w);
            }
        }
        for (; j + 8 <= m; j += 8) {
            const int jj = j + half;
            int   d[4]; float e[4];
            #pragma unroll
            for (int k = 0; k < 4; ++k) {
                d[k] = __shfl(pd, jj + 2 * k);
                e[k] = __shfl(pe, jj + 2 * k);
            }
            ushort4 u[4];
            #pragma unroll
            for (int k = 0; k < 4; ++k) u[k] = hb4[(size_t)d[k] * 32 + hl];
            #pragma unroll
            for (int k = 0; k < 4; ++k) {
                rs    += e[k];
                acc.x += e[k] * bf2f(u[k].x);
                acc.y += e[k] * bf2f(u[k].y);
                acc.z += e[k] * bf2f(u[k].z);
                acc.w += e[k] * bf2f(u[k].w);
            }
        }
        for (; j + 2 <= m; j += 2) {
            const int jj = j + half;
            const int   dd = __shfl(pd, jj);
            const float ee = __shfl(pe, jj);
            const ushort4 u = hb4[(size_t)dd * 32 + hl];
            rs += ee;
            acc.x += ee * bf2f(u.x);
            acc.y += ee * bf2f(u.y);
            acc.z += ee * bf2f(u.z);
            acc.w += ee * bf2f(u.w);
        }
        if (j < m) {                          // single leftover edge
            const int   dd = __shfl(pd, j);   // uniform source index
            float       ee = __shfl(pe, j);
            if (half == 1) ee = 0.0f;
            const ushort4 u = hb4[(size_t)dd * 32 + hl];
            rs += ee;
            acc.x += ee * bf2f(u.x);
            acc.y += ee * bf2f(u.y);
            acc.z += ee * bf2f(u.z);
            acc.w += ee * bf2f(u.w);
        }
    }

    acc.x += __shfl_xor(acc.x, 32);
    acc.y += __shfl_xor(acc.y, 32);
    acc.z += __shfl_xor(acc.z, 32);
    acc.w += __shfl_xor(acc.w, 32);
    rs    += __shfl_xor(rs, 32);

    if (half == 0) {
        const float inv = 1.0f / rs;
        float4 o;
        o.x = fmaxf(acc.x * inv, 0.0f);
        o.y = fmaxf(acc.y * inv, 0.0f);
        o.z = fmaxf(acc.z * inv, 0.0f);
        o.w = fmaxf(acc.w * inv, 0.0f);
        reinterpret_cast<float4*>(out)[(size_t)node * 32 + hl] = o;
    }
}

// ---------------------------------------------------------------------------
// K4 (f32): r4/r5-proven gather for the mid-tier ws fallback.
// ---------------------------------------------------------------------------
__global__ void gather_f32_kernel(const float* __restrict__ h,
                                  const int* __restrict__ row_start,
                                  const int2* __restrict__ pairs,
                                  float* __restrict__ out) {
    const int gtid = blockIdx.x * blockDim.x + threadIdx.x;
    const int node = gtid >> 6;
    const int lane = threadIdx.x & 63;
    if (node >= N_NODES) return;

    const int beg = row_start[node];
    const int end = row_start[node + 1];

    const int half = lane >> 5;
    const int hl   = lane & 31;
    const float4* __restrict__ h4 = reinterpret_cast<const float4*>(h);

    float4 acc = make_float4(0.0f, 0.0f, 0.0f, 0.0f);
    float rs = 0.0f;

    for (int base = beg; base < end; base += 64) {
        const int m = min(64, end - base);
        int pd = 0; float pe = 0.0f;
        if (lane < m) {
            const int2 pr = pairs[base + lane];
            pd = pr.x;
            pe = __int_as_float(pr.y);
        }
        int j = 0;
        for (; j + 8 <= m; j += 8) {
            const int jj = j + half;
            int   d[4]; float e[4];
            #pragma unroll
            for (int k = 0; k < 4; ++k) {
                d[k] = __shfl(pd, jj + 2 * k);
                e[k] = __shfl(pe, jj + 2 * k);
            }
            float4 v[4];
            #pragma unroll
            for (int k = 0; k < 4; ++k) v[k] = h4[(size_t)d[k] * 32 + hl];
            #pragma unroll
            for (int k = 0; k < 4; ++k) {
                rs    += e[k];
                acc.x += e[k] * v[k].x;
                acc.y += e[k] * v[k].y;
                acc.z += e[k] * v[k].z;
                acc.w += e[k] * v[k].w;
            }
        }
        for (; j + 2 <= m; j += 2) {
            const int jj = j + half;
            const int   dd = __shfl(pd, jj);
            const float ee = __shfl(pe, jj);
            const float4 v = h4[(size_t)dd * 32 + hl];
            rs += ee;
            acc.x += ee * v.x;
            acc.y += ee * v.y;
            acc.z += ee * v.z;
            acc.w += ee * v.w;
        }
        if (j < m) {
            const int   dd = __shfl(pd, j);
            float       ee = __shfl(pe, j);
            if (half == 1) ee = 0.0f;
            const float4 v = h4[(size_t)dd * 32 + hl];
            rs += ee;
            acc.x += ee * v.x;
            acc.y += ee * v.y;
            acc.z += ee * v.z;
            acc.w += ee * v.w;
        }
    }

    acc.x += __shfl_xor(acc.x, 32);
    acc.y += __shfl_xor(acc.y, 32);
    acc.z += __shfl_xor(acc.z, 32);
    acc.w += __shfl_xor(acc.w, 32);
    rs    += __shfl_xor(rs, 32);

    if (half == 0) {
        const float inv = 1.0f / rs;
        float4 o;
        o.x = fmaxf(acc.x * inv, 0.0f);
        o.y = fmaxf(acc.y * inv, 0.0f);
        o.z = fmaxf(acc.z * inv, 0.0f);
        o.w = fmaxf(acc.w * inv, 0.0f);
        reinterpret_cast<float4*>(out)[(size_t)node * 32 + hl] = o;
    }
}

// ---------------------------------------------------------------------------
// Last-resort fallback (atomic path).
// ---------------------------------------------------------------------------
__global__ void score_kernel(const float* __restrict__ h,
                             const float* __restrict__ a,
                             float* __restrict__ s_left,
                             float* __restrict__ s_right) {
    const int gtid = blockIdx.x * blockDim.x + threadIdx.x;
    const int node = gtid >> 6;
    const int lane = threadIdx.x & 63;
    if (node >= N_NODES) return;
    const float2 hv = reinterpret_cast<const float2*>(h + (size_t)node * F_DIM)[lane];
    const float2 al = reinterpret_cast<const float2*>(a)[lane];
    const float2 ar = reinterpret_cast<const float2*>(a + F_DIM)[lane];
    float pl = hv.x * al.x + hv.y * al.y;
    float pr = hv.x * ar.x + hv.y * ar.y;
    #pragma unroll
    for (int off = 32; off > 0; off >>= 1) {
        pl += __shfl_down(pl, off);
        pr += __shfl_down(pr, off);
    }
    if (lane == 0) { s_left[node] = pl; s_right[node] = pr; }
}

__global__ void edge_atomic_kernel(const float* __restrict__ h,
                                   const int* __restrict__ src,
                                   const int* __restrict__ dst,
                                   const float* __restrict__ s_left,
                                   const float* __restrict__ s_right,
                                   float* __restrict__ out,
                                   float* __restrict__ rowsum) {
    const int gtid = blockIdx.x * blockDim.x + threadIdx.x;
    const int e = gtid >> 6;
    const int lane = threadIdx.x & 63;
    if (e >= E_EDGES) return;
    const int s = src[e];
    const int d = dst[e];
    const float score = s_left[s] + s_right[d];
    const float lr = score > 0.0f ? score : ALPHA * score;
    const float ee = __expf(-lr);
    if (lane == 0) atomicAdd(&rowsum[s], ee);
    const float2 hv = reinterpret_cast<const float2*>(h + (size_t)d * F_DIM)[lane];
    float* o = out + (size_t)s * F_DIM + (size_t)lane * 2;
    atomicAdd(o,     ee * hv.x);
    atomicAdd(o + 1, ee * hv.y);
}

__global__ void finalize_kernel(float* __restrict__ out,
                                const float* __restrict__ rowsum) {
    const int i = blockIdx.x * blockDim.x + threadIdx.x;
    const int total = N_NODES * (F_DIM / 4);
    if (i >= total) return;
    const int n = i / (F_DIM / 4);
    const float inv = 1.0f / rowsum[n];
    float4 v = reinterpret_cast<float4*>(out)[i];
    v.x = fmaxf(v.x * inv, 0.0f);
    v.y = fmaxf(v.y * inv, 0.0f);
    v.z = fmaxf(v.z * inv, 0.0f);
    v.w = fmaxf(v.w * inv, 0.0f);
    reinterpret_cast<float4*>(out)[i] = v;
}

extern "C" void kernel_launch(void* const* d_in, const int* in_sizes, int n_in,
                              void* d_out, int out_size, void* d_ws, size_t ws_size,
                              hipStream_t stream) {
    const float* h    = (const float*)d_in[0];   // [N, F]
    const float* a    = (const float*)d_in[1];   // [1, 2F]
    const int*   edge = (const int*)d_in[2];     // [2, E]
    const int*   src  = edge;
    const int*   dst  = edge + E_EDGES;
    float* out = (float*)d_out;

    const int wpb = 256 / 64;

    // --- common CSR buffers ---
    char* wp = (char*)d_ws;
    int2*  pairs    = (int2*)wp;      wp += (size_t)E_EDGES * sizeof(int2);       // 12.8MB
    float* s_left   = (float*)wp;     wp += (size_t)N_NODES * sizeof(float);
    float* s_right  = (float*)wp;     wp += (size_t)N_NODES * sizeof(float);
    int*   counts   = (int*)wp;       wp += (size_t)N_NODES * sizeof(int);
    int*   cursor   = (int*)wp;       wp += (size_t)N_NODES * sizeof(int);
    int*   row_start= (int*)wp;       wp += (size_t)(N_NODES + 1) * sizeof(int);
    int*   partials = (int*)wp;       wp += 128 * sizeof(int);
    const size_t needed_f32 = (size_t)(wp - (char*)d_ws);
    unsigned short* h_bf16 = (unsigned short*)wp;   // +25.6MB for the bf16 tier
    const size_t needed_bf16 = needed_f32 + (size_t)N_NODES * F_DIM * sizeof(unsigned short);

    if (ws_size < needed_f32) {
        // -------- last resort: atomic path (needs only 1.2 MB) --------
        float* fsl = (float*)d_ws;
        float* fsr = fsl + N_NODES;
        float* frs = fsr + N_NODES;
        hipMemsetAsync(d_out, 0, (size_t)N_NODES * F_DIM * sizeof(float), stream);
        hipMemsetAsync(frs, 0, (size_t)N_NODES * sizeof(float), stream);
        score_kernel<<<(N_NODES + wpb - 1) / wpb, 256, 0, stream>>>(h, a, fsl, fsr);
        edge_atomic_kernel<<<(E_EDGES + wpb - 1) / wpb, 256, 0, stream>>>(
            h, src, dst, fsl, fsr, out, frs);
        const int total = N_NODES * (F_DIM / 4);
        finalize_kernel<<<(total + 255) / 256, 256, 0, stream>>>(out, frs);
        return;
    }

    const bool use_bf16 = (ws_size >= needed_bf16);

    hipMemsetAsync(counts, 0, (size_t)N_NODES * sizeof(int), stream);

    if (use_bf16) {
        fused_score_hist_kernel<<<SCORE_BLOCKS + HIST_BLOCKS, 256, 0, stream>>>(
            h, a, s_left, s_right, h_bf16, src, counts);
    } else {
        // no bf16 copy: reuse the fused kernel shape via score + plain hist
        score_kernel<<<(N_NODES + wpb - 1) / wpb, 256, 0, stream>>>(h, a, s_left, s_right);
        fused_score_hist_kernel<<<HIST_BLOCKS, 256, 0, stream>>>(
            h, a, s_left, s_right, (unsigned short*)pairs /*unused: blocks < SCORE? no*/,
            src, counts);
    }

    scan_block_kernel<<<NUM_SCAN_BLOCKS, SCAN_BLOCK, 0, stream>>>(counts, row_start, partials);
    scan_partials_kernel<<<1, 128, 0, stream>>>(partials);
    add_offsets_kernel<<<(N_NODES + 255) / 256, 256, 0, stream>>>(row_start, partials, cursor);

    scatter_kernel<<<(E_EDGES + 255) / 256, 256, 0, stream>>>(
        src, dst, s_left, s_right, cursor, pairs);

    if (use_bf16) {
        gather_bf16_kernel<<<(N_NODES + wpb - 1) / wpb, 256, 0, stream>>>(
            h_bf16, row_start, pairs, out);
    } else {
        gather_f32_kernel<<<(N_NODES + wpb - 1) / wpb, 256, 0, stream>>>(
            h, row_start, pairs, out);
    }
}